// Round 12
// baseline (2562.028 us; speedup 1.0000x reference)
//
#include <hip/hip_runtime.h>

// File-scope: forbid implicit fma contraction (keeps every a*b+c as two
// single-rounded IEEE ops, matching the numpy reference bit-for-bit).
#pragma clang fp contract(off)

#define NPOINT 2048
#define NSAMPLE 32
#define NPTS 8192
#define NB 4
#define CH 16
#define FPS_THREADS 512
#define PTS_PER_THREAD (NPTS / FPS_THREADS) /* 16 */
#define PAIRS (PTS_PER_THREAD / 2)          /* 8 */
#define FPS_WAVES (FPS_THREADS / 64)        /* 8 */
#define BQ_BLOCKS 252
#define BQ_WAVES (BQ_BLOCKS * 8) /* 2016 */
#define SENT 0xFFFFFFFFu /* -NaN: unreachable by Gaussian input, memset-able */

typedef unsigned long long u64;
typedef float v2f __attribute__((ext_vector_type(2)));

// Output layout (flat float32, concatenated in reference return order)
#define OFF_NEWXYZ 0
#define OFF_NEWPTS (NB * NPOINT * 3)                          /* 24576 */
#define OFF_IDX (OFF_NEWPTS + NB * NPOINT * NSAMPLE * CH)     /* 4218880 */
#define OFF_GXYZ (OFF_IDX + NB * NPOINT * NSAMPLE)            /* 4481024 */

template <int CTRL>
__device__ __forceinline__ float dpp_fmax(float v) {
  // bound_ctrl=true -> 0-fill; distances are >= 0 so 0 is a safe identity.
  int o = __builtin_amdgcn_update_dpp(0, __float_as_int(v), CTRL, 0xf, 0xf, true);
  return fmaxf(v, __int_as_float(o));
}

// Workgroup barrier WITHOUT the vmcnt(0) drain __syncthreads carries (R27's
// win: -160us). LDS cross-wave correctness only needs each wave's own ds ops
// complete before s_barrier (lgkmcnt); global sc1 publish stores stay in
// flight across barriers forever.
__device__ __forceinline__ void lgkm_barrier() {
  asm volatile("s_waitcnt lgkmcnt(0)" ::: "memory");
  __builtin_amdgcn_s_barrier();
}

// Cache-bypassing (agent-scope, RELAXED) accessors. gfx950 per-XCD L2s are
// non-coherent: agent ACQUIRE emits cache invalidates, agent RELEASE emits
// L2 writebacks (R24: +370us producer convoy). Relaxed agent ops just set
// the sc bits -- direct access to the coherence point, no flush side
// effects. Word-granular sentinel coding makes ordering irrelevant.
__device__ __forceinline__ void st_sc1(float* p, float v) {
  __hip_atomic_store(p, v, __ATOMIC_RELAXED, __HIP_MEMORY_SCOPE_AGENT);
}
__device__ __forceinline__ unsigned ld_sc1_u(const unsigned* p) {
  return __hip_atomic_load(p, __ATOMIC_RELAXED, __HIP_MEMORY_SCOPE_AGENT);
}

// ---------------- Ball-query per-query body ---------------------------------
__device__ __forceinline__ void write_slot(float* __restrict__ out,
                                           const float* __restrict__ base,
                                           int b, int qi, int s, int p,
                                           float4 r0, float qx, float qy,
                                           float qz) {
  float dx = __fsub_rn(r0.x, qx);
  float dy = __fsub_rn(r0.y, qy);
  float dz = __fsub_rn(r0.z, qz);
  size_t qs = (size_t)b * NPOINT + qi;
  out[OFF_IDX + qs * NSAMPLE + s] = (float)p;  // idx stored as float32
  float* g = out + OFF_GXYZ + (qs * NSAMPLE + s) * 3;
  g[0] = dx;
  g[1] = dy;
  g[2] = dz;
  const float* row = base + (size_t)p * CH;
  float4 r1 = *reinterpret_cast<const float4*>(row + 4);
  float4 r2 = *reinterpret_cast<const float4*>(row + 8);
  float4 r3 = *reinterpret_cast<const float4*>(row + 12);
  float* np_ = out + OFF_NEWPTS + (qs * NSAMPLE + s) * CH;
  *reinterpret_cast<float4*>(np_ + 0) = make_float4(dx, dy, dz, r0.w);
  *reinterpret_cast<float4*>(np_ + 4) = r1;
  *reinterpret_cast<float4*>(np_ + 8) = r2;
  *reinterpret_cast<float4*>(np_ + 12) = r3;
}

// R23 4-wide chunk-group scan (bit-identical outputs to the serial scan:
// writes gated by pos<NSAMPLE, cnt monotone, 'first' sticky -> up to 3
// extra processed chunks are output-invisible). Coords passed in (the
// fused consumer already holds them from the sentinel poll).
__device__ __forceinline__ void ballq_one(const float* __restrict__ in,
                                          float* __restrict__ out, int b,
                                          int qi, int lane, float qx,
                                          float qy, float qz) {
  const float* base = in + (size_t)b * NPTS * CH;
  // Mirror reference: d2 = sum(q*q) + sum(p*p) - 2*(q . p)
  float qn = __fadd_rn(__fadd_rn(__fmul_rn(qx, qx), __fmul_rn(qy, qy)),
                       __fmul_rn(qz, qz));
  int cnt = 0;
  int first = 0;
  bool have_first = false;
  for (int cg = 0; cg < NPTS / 64 && cnt < NSAMPLE; cg += 4) {
    float4 r[4];
#pragma unroll
    for (int u = 0; u < 4; ++u)
      r[u] = *reinterpret_cast<const float4*>(
          base + (size_t)((cg + u) * 64 + lane) * CH);
#pragma unroll
    for (int u = 0; u < 4; ++u) {
      const int chunk = cg + u;
      const int p = chunk * 64 + lane;
      const float4 r0 = r[u];
      float pn =
          __fadd_rn(__fadd_rn(__fmul_rn(r0.x, r0.x), __fmul_rn(r0.y, r0.y)),
                    __fmul_rn(r0.z, r0.z));
      float dot =
          __fadd_rn(__fadd_rn(__fmul_rn(qx, r0.x), __fmul_rn(qy, r0.y)),
                    __fmul_rn(qz, r0.z));
      float d2 = __fsub_rn(__fadd_rn(qn, pn), __fmul_rn(2.0f, dot));
      bool in_r = d2 < 1.0f;  // RADIUS^2
      unsigned long long mask = __ballot(in_r);
      if (!have_first && mask) {
        first = chunk * 64 + __builtin_ctzll(mask);
        have_first = true;
      }
      int pos = cnt + __popcll(mask & ((1ull << lane) - 1ull));
      if (in_r && pos < NSAMPLE)
        write_slot(out, base, b, qi, pos, p, r0, qx, qy, qz);
      cnt += __popcll(mask);
    }
  }
  if (cnt < NSAMPLE) {
    int s = cnt + lane;
    if (s < NSAMPLE) {
      float4 r0 = *reinterpret_cast<const float4*>(base + (size_t)first * CH);
      write_slot(out, base, b, qi, s, first, r0, qx, qy, qz);
    }
  }
}

// ---------------- R28 fused kernel: coords ride the keys, v3 ----------------
// R27 (verified 1709us dispatch / 1747.5 total): sentinel publish +
// lgkm-only barriers removed every vmcnt drain. Remaining serial head:
// barrier -> slot ds_read(~140cy) -> tree(~60) -> DEPENDENT lpxyz[gi]
// ds_read(~140) -> dist loop. R28 removes the second hop with the three
// prior failure modes engineered out:
//   R20 (+1100): in-loop coord tracking -> VGPR demotion. AVOIDED: no
//     in-loop state; extraction is post-loop, transient regs only.
//   R21 (+410): in-loop asm broke scheduling. AVOIDED: loop body is
//     BYTE-IDENTICAL; asm only at barriers (already in R27).
//   R22 (+620): per-lane scattered lpxyz[besti] b128 reads -> massive LDS
//     bank conflicts (512 random float4 reads/iter). AVOIDED: no scattered
//     reads; winner coords come from the lane's own pxv/pyv/pzv registers
//     via a 7-step cndmask tree, overlapped with the DPP chain's latency.
// Tail: extraction (independent of DPP) -> winner lane publishes key b64 +
// coords b128. Head: keys + 8 coord slots in ONE latency window; 21-cndmask
// 3-level select on ws = gi>>10 (contiguous ownership: wave = besti>>10).
// lpxyz is now store-only but KEPT + asm memory clobber: its 128KB is the
// occupancy fence (1 block/CU; producers must not share CUs with consumers
// -- R18 issue-stealing). tid0's newxyz publish uses the selected coords
// (no LDS read on wave 0's path).
// Tie-breaks (exact jnp.argmax lowest-index): parity checks .x first; strict
// '>' keeps lowest jp; ballot-ctz keeps lowest lane; key low word (8191-idx)
// keeps lowest wave. Keys globally unique -> no cross-wave ties.
__global__ __launch_bounds__(FPS_THREADS)
__attribute__((amdgpu_waves_per_eu(2))) void fused_kernel(
    const float* __restrict__ in, float* __restrict__ out) {
  __shared__ float4 lpxyz[NPTS];  // 128 KB occupancy fence (store-only)
  __shared__ alignas(16) u64 slots_k[2][FPS_WAVES];    // per-wave argmax keys
  __shared__ alignas(16) float4 slots_c[2][FPS_WAVES]; // per-wave winner coords

  const int tid = threadIdx.x;
  const int lane = tid & 63;

  if (blockIdx.x >= NB) {
    // ------------------ ballq consumer role ------------------
    const int slot = (blockIdx.x - NB) * 8 + (tid >> 6);  // 0..2015
    for (int g = slot; g < NB * NPOINT; g += BQ_WAVES) {
      const int qi = g >> 2;  // qi-major: unlocks in production order
      const int b = g & 3;
      const unsigned* qw = reinterpret_cast<const unsigned*>(
          out + OFF_NEWXYZ + ((size_t)b * NPOINT + qi) * 3);
      unsigned x, y, z;
      for (;;) {  // wave-uniform spin (b, qi uniform across the wave)
        x = ld_sc1_u(&qw[0]);
        y = ld_sc1_u(&qw[1]);
        z = ld_sc1_u(&qw[2]);
        if (x != SENT && y != SENT && z != SENT) break;
        __builtin_amdgcn_s_sleep(8);  // ~0.2us between polls
      }
      ballq_one(in, out, b, qi, lane, __uint_as_float(x), __uint_as_float(y),
                __uint_as_float(z));
    }
    return;
  }

  // ------------------ fps producer role ------------------
  const int b = blockIdx.x;
  const int wv = tid >> 6;
  const float* base = in + (size_t)b * NPTS * CH;
  float* gnew = out + OFF_NEWXYZ + (size_t)b * NPOINT * 3;

  v2f pxv[PAIRS], pyv[PAIRS], pzv[PAIRS], dv[PAIRS];
#pragma unroll
  for (int jp = 0; jp < PAIRS; ++jp) {
    int p0 = tid * PTS_PER_THREAD + 2 * jp;
    float4 r0 = *reinterpret_cast<const float4*>(base + (size_t)p0 * CH);
    float4 r1 = *reinterpret_cast<const float4*>(base + (size_t)(p0 + 1) * CH);
    pxv[jp] = (v2f){r0.x, r1.x};
    pyv[jp] = (v2f){r0.y, r1.y};
    pzv[jp] = (v2f){r0.z, r1.z};
    lpxyz[p0] = r0;
    lpxyz[p0 + 1] = r1;
    dv[jp] = (v2f){__builtin_inff(), __builtin_inff()};
  }
  // Keep the (now store-only) lpxyz allocation: the clobber tells the
  // compiler the stores may be observed -> no LDS DCE -> 128KB stays ->
  // 1 block/CU. One-time, outside the loop: no scheduling impact.
  asm volatile("" ::: "memory");
  // Prime parity-0: slot 0 = (+inf, idx 0) wins iteration 0; its coords are
  // point 0's (global read, L2-hot from staging). Dummies (key 0) never win.
  if (tid < FPS_WAVES) {
    slots_k[0][tid] = (tid == 0) ? (((u64)0x7f800000u << 32) | 8191u) : 0ull;
    slots_c[0][tid] = make_float4(0.f, 0.f, 0.f, 0.f);
    slots_c[1][tid] = make_float4(0.f, 0.f, 0.f, 0.f);
  }
  if (tid == 0)
    slots_c[0][0] = make_float4(base[0], base[1], base[2], 0.f);

  for (int it = 0; it < NPOINT; ++it) {
    lgkm_barrier();  // separates slot writes (it-1) from reads (it);
                     // LDS-only drain -- publish stores stay in flight
    const int par = it & 1;
    // ONE latency window: 4 key b128 + 8 coord b128 broadcast reads.
    const ulonglong2* sp =
        reinterpret_cast<const ulonglong2*>(&slots_k[par][0]);
    const ulonglong2 s01 = sp[0];
    const ulonglong2 s23 = sp[1];
    const ulonglong2 s45 = sp[2];
    const ulonglong2 s67 = sp[3];
    const float4 c0 = slots_c[par][0];
    const float4 c1 = slots_c[par][1];
    const float4 c2 = slots_c[par][2];
    const float4 c3 = slots_c[par][3];
    const float4 c4 = slots_c[par][4];
    const float4 c5 = slots_c[par][5];
    const float4 c6 = slots_c[par][6];
    const float4 c7 = slots_c[par][7];
    // 7-compare u64 max (keys globally unique -> no ties).
    u64 ka = (s01.y > s01.x) ? s01.y : s01.x;
    u64 kb = (s23.y > s23.x) ? s23.y : s23.x;
    u64 kc = (s45.y > s45.x) ? s45.y : s45.x;
    u64 kd = (s67.y > s67.x) ? s67.y : s67.x;
    ka = (kb > ka) ? kb : ka;
    kc = (kd > kc) ? kd : kc;
    const u64 k = (kc > ka) ? kc : ka;
    const unsigned gi = 8191u - (unsigned)k;  // low 32 bits = 8191-idx
    // Winner coords: 3-level cndmask tree on the owner-wave index (21 ops
    // replaces the ~140cy dependent lpxyz[gi] read).
    const unsigned ws = gi >> 10;  // 1024 points per wave
    const bool b0 = (ws & 1u) != 0u;
    const bool b1 = (ws & 2u) != 0u;
    const bool b2 = (ws & 4u) != 0u;
    const float t0x = b0 ? c1.x : c0.x, t0y = b0 ? c1.y : c0.y,
                t0z = b0 ? c1.z : c0.z;
    const float t1x = b0 ? c3.x : c2.x, t1y = b0 ? c3.y : c2.y,
                t1z = b0 ? c3.z : c2.z;
    const float t2x = b0 ? c5.x : c4.x, t2y = b0 ? c5.y : c4.y,
                t2z = b0 ? c5.z : c4.z;
    const float t3x = b0 ? c7.x : c6.x, t3y = b0 ? c7.y : c6.y,
                t3z = b0 ? c7.z : c6.z;
    const float u0x = b1 ? t1x : t0x, u0y = b1 ? t1y : t0y,
                u0z = b1 ? t1z : t0z;
    const float u1x = b1 ? t3x : t2x, u1y = b1 ? t3y : t2y,
                u1z = b1 ? t3z : t2z;
    const float gx = b2 ? u1x : u0x;
    const float gy = b2 ? u1y : u0y;
    const float gz = b2 ? u1z : u0z;
    if (tid == 0) {  // publish winner: 3 sc1 dwords, fire-and-forget
      st_sc1(&gnew[it * 3 + 0], gx);
      st_sc1(&gnew[it * 3 + 1], gy);
      st_sc1(&gnew[it * 3 + 2], gz);
    }
    // Distance update: BYTE-IDENTICAL to the verified loop (DO NOT TOUCH).
    float bestv = -1.0f;
    float bestx = -1.0f;
    int bestjp = 0;
#pragma unroll
    for (int jp = 0; jp < PAIRS; ++jp) {
      v2f dx = pxv[jp] - gx;
      v2f dy = pyv[jp] - gy;
      v2f dz = pzv[jp] - gz;
      v2f nd = (dx * dx + dy * dy) + dz * dz;
      v2f dn = {fminf(dv[jp].x, nd.x), fminf(dv[jp].y, nd.y)};
      dv[jp] = dn;
      float pm = fmaxf(dn.x, dn.y);
      bool t = pm > bestv;  // strict: lowest jp wins ties
      bestjp = t ? jp : bestjp;
      bestx = t ? dn.x : bestx;
      bestv = fmaxf(bestv, pm);
    }
    // Within-pair parity: .x first (lower index) on ties.
    const bool selx = (bestx == bestv);
    const int bestj = 2 * bestjp + (selx ? 0 : 1);
    const unsigned besti = (unsigned)(tid * PTS_PER_THREAD + bestj);
    // Candidate-coord extraction from own registers (no LDS, no conflicts);
    // independent of the DPP chain -> overlaps its latency.
    v2f ex = pxv[0], ey = pyv[0], ez = pzv[0];
#pragma unroll
    for (int jp = 1; jp < PAIRS; ++jp) {
      bool s = (bestjp == jp);
      ex = s ? pxv[jp] : ex;
      ey = s ? pyv[jp] : ey;
      ez = s ? pzv[jp] : ez;
    }
    const float wx = selx ? ex.x : ex.y;
    const float wy = selx ? ey.x : ey.y;
    const float wz = selx ? ez.x : ez.y;
    // Wave max via 6 DPP rounds -> lane 63; ballot -> lowest matching lane.
    float wm = bestv;
    wm = dpp_fmax<0x111>(wm);  // row_shr:1
    wm = dpp_fmax<0x112>(wm);  // row_shr:2
    wm = dpp_fmax<0x114>(wm);  // row_shr:4
    wm = dpp_fmax<0x118>(wm);  // row_shr:8
    wm = dpp_fmax<0x142>(wm);  // row_bcast15
    wm = dpp_fmax<0x143>(wm);  // row_bcast31
    const float swm =
        __int_as_float(__builtin_amdgcn_readlane(__float_as_int(wm), 63));
    const u64 wbal = __ballot(bestv == swm);
    const int wl = (int)__builtin_ctzll(wbal);
    if (lane == wl) {  // tiny tail: key b64 + coords b128
      slots_k[par ^ 1][wv] =
          ((u64)__float_as_uint(bestv) << 32) | (8191u - besti);
      slots_c[par ^ 1][wv] = make_float4(wx, wy, wz, 0.f);
    }
  }
  // No epilogue: newxyz fully published in-loop; dispatch completion
  // guarantees all stores retire before host readback.
}

extern "C" void kernel_launch(void* const* d_in, const int* in_sizes, int n_in,
                              void* d_out, int out_size, void* d_ws,
                              size_t ws_size, hipStream_t stream) {
  (void)in_sizes;
  (void)n_in;
  (void)out_size;
  (void)d_ws;
  (void)ws_size;
  const float* in = (const float*)d_in[0];
  float* out = (float*)d_out;
  // Poison newxyz with SENT (0xFF bytes = -NaN) so data doubles as the
  // readiness flag. Stream-ordered: completes before the kernel starts.
  hipMemsetAsync(out + OFF_NEWXYZ, 0xFF, (size_t)NB * NPOINT * 3 * sizeof(float),
                 stream);
  fused_kernel<<<NB + BQ_BLOCKS, FPS_THREADS, 0, stream>>>(in, out);
}

// Round 13
// 1736.363 us; speedup vs baseline: 1.4755x; 1.4755x over previous
//
#include <hip/hip_runtime.h>

// File-scope: forbid implicit fma contraction (keeps every a*b+c as two
// single-rounded IEEE ops, matching the numpy reference bit-for-bit).
#pragma clang fp contract(off)

#define NPOINT 2048
#define NSAMPLE 32
#define NPTS 8192
#define NB 4
#define CH 16
#define FPS_THREADS 512
#define PTS_PER_THREAD (NPTS / FPS_THREADS) /* 16 */
#define PAIRS (PTS_PER_THREAD / 2)          /* 8 */
#define FPS_WAVES (FPS_THREADS / 64)        /* 8 */
#define BQ_BLOCKS 252
#define BQ_WAVES (BQ_BLOCKS * 8) /* 2016 */
#define SENT 0xFFFFFFFFu /* -NaN: unreachable by Gaussian input, memset-able */

typedef unsigned long long u64;
typedef float v2f __attribute__((ext_vector_type(2)));

// Output layout (flat float32, concatenated in reference return order)
#define OFF_NEWXYZ 0
#define OFF_NEWPTS (NB * NPOINT * 3)                          /* 24576 */
#define OFF_IDX (OFF_NEWPTS + NB * NPOINT * NSAMPLE * CH)     /* 4218880 */
#define OFF_GXYZ (OFF_IDX + NB * NPOINT * NSAMPLE)            /* 4481024 */

// ---------------------------------------------------------------------------
// SESSION LEDGER (final). Verified optimum: R27 (this file) = 1747.5us total
// (fused dispatch 1709us), from 1844.8us at session start. What worked:
//   R23 (+5us): ballq 4-wide chunk-group loads.
//   R27 (-92us): producer-consumer fusion with (a) sentinel-coded word-
//     atomic publishes (data IS the flag; no ordering ops at all) and
//     (b) lgkm-only barriers (no vmcnt(0) drain -> publish stores float).
// What failed (all reverted):
//   R18 spin-poll slots       +152us (poll issue + s_sleep quantization)
//   R19 256t/1-wave           +385us (latency exposed + VGPR squeeze)
//   R20 coords+in-loop track +1100us (VGPR 88->60 allocator demotion)
//   R21 inline-asm pk loop    +410us (broke scheduler; loop already packed)
//   R22 spec lpxyz[besti]     +620us (512 scattered b128 -> bank conflicts)
//   R24 acquire/release sync  +370us (agent acq/rel = cache inv/wb ops)
//   R26 flag-line spreading     ~0   (contention wasn't the cost; vmcnt was)
//   R28 coords-ride-keys v3   +815us (LDS DCE killed the 128KB occupancy
//         fence -> consumers invaded producer CUs; extraction tree re-
//         triggered VGPR demotion. Structure rejects ALL dataflow edits.)
// Conclusion: the fps loop + register file + LDS footprint is a fragile
// equilibrium. It accepts sync-cost removal only. DO NOT TOUCH the loop,
// the LDS layout, the occupancy attributes, or add any in/post-loop state.
// ---------------------------------------------------------------------------

template <int CTRL>
__device__ __forceinline__ float dpp_fmax(float v) {
  // bound_ctrl=true -> 0-fill; distances are >= 0 so 0 is a safe identity.
  int o = __builtin_amdgcn_update_dpp(0, __float_as_int(v), CTRL, 0xf, 0xf, true);
  return fmaxf(v, __int_as_float(o));
}

// Workgroup barrier WITHOUT the vmcnt(0) drain __syncthreads carries (R27's
// win). LDS cross-wave correctness only needs each wave's own ds ops
// complete before s_barrier (lgkmcnt); global sc1 publish stores stay in
// flight across barriers forever.
__device__ __forceinline__ void lgkm_barrier() {
  asm volatile("s_waitcnt lgkmcnt(0)" ::: "memory");
  __builtin_amdgcn_s_barrier();
}

// Cache-bypassing (agent-scope, RELAXED) accessors. gfx950 per-XCD L2s are
// non-coherent: agent ACQUIRE emits cache invalidates, agent RELEASE emits
// L2 writebacks (R24: +370us producer convoy). Relaxed agent ops just set
// the sc bits -- direct access to the coherence point, no flush side
// effects. Word-granular sentinel coding makes ordering irrelevant.
__device__ __forceinline__ void st_sc1(float* p, float v) {
  __hip_atomic_store(p, v, __ATOMIC_RELAXED, __HIP_MEMORY_SCOPE_AGENT);
}
__device__ __forceinline__ unsigned ld_sc1_u(const unsigned* p) {
  return __hip_atomic_load(p, __ATOMIC_RELAXED, __HIP_MEMORY_SCOPE_AGENT);
}

// ---------------- Ball-query per-query body ---------------------------------
__device__ __forceinline__ void write_slot(float* __restrict__ out,
                                           const float* __restrict__ base,
                                           int b, int qi, int s, int p,
                                           float4 r0, float qx, float qy,
                                           float qz) {
  float dx = __fsub_rn(r0.x, qx);
  float dy = __fsub_rn(r0.y, qy);
  float dz = __fsub_rn(r0.z, qz);
  size_t qs = (size_t)b * NPOINT + qi;
  out[OFF_IDX + qs * NSAMPLE + s] = (float)p;  // idx stored as float32
  float* g = out + OFF_GXYZ + (qs * NSAMPLE + s) * 3;
  g[0] = dx;
  g[1] = dy;
  g[2] = dz;
  const float* row = base + (size_t)p * CH;
  float4 r1 = *reinterpret_cast<const float4*>(row + 4);
  float4 r2 = *reinterpret_cast<const float4*>(row + 8);
  float4 r3 = *reinterpret_cast<const float4*>(row + 12);
  float* np_ = out + OFF_NEWPTS + (qs * NSAMPLE + s) * CH;
  *reinterpret_cast<float4*>(np_ + 0) = make_float4(dx, dy, dz, r0.w);
  *reinterpret_cast<float4*>(np_ + 4) = r1;
  *reinterpret_cast<float4*>(np_ + 8) = r2;
  *reinterpret_cast<float4*>(np_ + 12) = r3;
}

// R23 4-wide chunk-group scan (bit-identical outputs to the serial scan:
// writes gated by pos<NSAMPLE, cnt monotone, 'first' sticky -> up to 3
// extra processed chunks are output-invisible). Coords passed in (the
// fused consumer already holds them from the sentinel poll).
__device__ __forceinline__ void ballq_one(const float* __restrict__ in,
                                          float* __restrict__ out, int b,
                                          int qi, int lane, float qx,
                                          float qy, float qz) {
  const float* base = in + (size_t)b * NPTS * CH;
  // Mirror reference: d2 = sum(q*q) + sum(p*p) - 2*(q . p)
  float qn = __fadd_rn(__fadd_rn(__fmul_rn(qx, qx), __fmul_rn(qy, qy)),
                       __fmul_rn(qz, qz));
  int cnt = 0;
  int first = 0;
  bool have_first = false;
  for (int cg = 0; cg < NPTS / 64 && cnt < NSAMPLE; cg += 4) {
    float4 r[4];
#pragma unroll
    for (int u = 0; u < 4; ++u)
      r[u] = *reinterpret_cast<const float4*>(
          base + (size_t)((cg + u) * 64 + lane) * CH);
#pragma unroll
    for (int u = 0; u < 4; ++u) {
      const int chunk = cg + u;
      const int p = chunk * 64 + lane;
      const float4 r0 = r[u];
      float pn =
          __fadd_rn(__fadd_rn(__fmul_rn(r0.x, r0.x), __fmul_rn(r0.y, r0.y)),
                    __fmul_rn(r0.z, r0.z));
      float dot =
          __fadd_rn(__fadd_rn(__fmul_rn(qx, r0.x), __fmul_rn(qy, r0.y)),
                    __fmul_rn(qz, r0.z));
      float d2 = __fsub_rn(__fadd_rn(qn, pn), __fmul_rn(2.0f, dot));
      bool in_r = d2 < 1.0f;  // RADIUS^2
      unsigned long long mask = __ballot(in_r);
      if (!have_first && mask) {
        first = chunk * 64 + __builtin_ctzll(mask);
        have_first = true;
      }
      int pos = cnt + __popcll(mask & ((1ull << lane) - 1ull));
      if (in_r && pos < NSAMPLE)
        write_slot(out, base, b, qi, pos, p, r0, qx, qy, qz);
      cnt += __popcll(mask);
    }
  }
  if (cnt < NSAMPLE) {
    int s = cnt + lane;
    if (s < NSAMPLE) {
      float4 r0 = *reinterpret_cast<const float4*>(base + (size_t)first * CH);
      write_slot(out, base, b, qi, s, first, r0, qx, qy, qz);
    }
  }
}

// ---------------- R27 fused kernel: sentinel-coded, drain-free --------------
// (Verified 1709us dispatch / 1747.5us total. Final form.)
// Grid = 4 fps blocks + 252 ballq blocks = 256; 131KB static LDS -> exactly
// 1 block/CU -> all 256 co-resident; spinning consumers own their CUs and
// can never steal issue slots from the producers.
//
// Producer (blocks 0..3): inner loop BYTE-IDENTICAL to the verified 1735us
// solo-fps form. lpxyz is genuinely read each iteration (winner-coords
// broadcast read) -- it is live, not a DCE hazard. newxyz output region is
// pre-poisoned with SENT (0xFF memset); tid0 publishes each winner's 3
// words at iteration it; each word is written once and is word-atomic ->
// the data IS the readiness flag: no fences, no flags, no workspace, no
// epilogue, no vmcnt drains anywhere in the loop.
// Consumers (blocks 4..255): 2016 waves, qi-major (g=qi*4+b) matching
// production order; poll own query's 3 words != SENT (relaxed sc1 +
// s_sleep), then run the R23 query body with the polled coords.
// Tie-breaks (exact jnp.argmax lowest-index): parity checks .x first; strict
// '>' keeps lowest jp; ballot-ctz keeps lowest lane; key low word (8191-idx)
// keeps lowest wave. Contiguous ownership (thread t owns t*16..t*16+15)
// keeps (wave,lane,j) order == global index order.
__global__ __launch_bounds__(FPS_THREADS)
__attribute__((amdgpu_waves_per_eu(2))) void fused_kernel(
    const float* __restrict__ in, float* __restrict__ out) {
  __shared__ float4 lpxyz[NPTS];  // 128 KB; winner coords: 1 ds_read_b128
  __shared__ alignas(16) u64 slots[2][FPS_WAVES];  // per-wave argmax keys

  const int tid = threadIdx.x;
  const int lane = tid & 63;

  if (blockIdx.x >= NB) {
    // ------------------ ballq consumer role ------------------
    const int slot = (blockIdx.x - NB) * 8 + (tid >> 6);  // 0..2015
    for (int g = slot; g < NB * NPOINT; g += BQ_WAVES) {
      const int qi = g >> 2;  // qi-major: unlocks in production order
      const int b = g & 3;
      const unsigned* qw = reinterpret_cast<const unsigned*>(
          out + OFF_NEWXYZ + ((size_t)b * NPOINT + qi) * 3);
      unsigned x, y, z;
      for (;;) {  // wave-uniform spin (b, qi uniform across the wave)
        x = ld_sc1_u(&qw[0]);
        y = ld_sc1_u(&qw[1]);
        z = ld_sc1_u(&qw[2]);
        if (x != SENT && y != SENT && z != SENT) break;
        __builtin_amdgcn_s_sleep(8);  // ~0.2us between polls
      }
      ballq_one(in, out, b, qi, lane, __uint_as_float(x), __uint_as_float(y),
                __uint_as_float(z));
    }
    return;
  }

  // ------------------ fps producer role ------------------
  const int b = blockIdx.x;
  const int wv = tid >> 6;
  const float* base = in + (size_t)b * NPTS * CH;
  float* gnew = out + OFF_NEWXYZ + (size_t)b * NPOINT * 3;

  v2f pxv[PAIRS], pyv[PAIRS], pzv[PAIRS], dv[PAIRS];
#pragma unroll
  for (int jp = 0; jp < PAIRS; ++jp) {
    int p0 = tid * PTS_PER_THREAD + 2 * jp;
    float4 r0 = *reinterpret_cast<const float4*>(base + (size_t)p0 * CH);
    float4 r1 = *reinterpret_cast<const float4*>(base + (size_t)(p0 + 1) * CH);
    pxv[jp] = (v2f){r0.x, r1.x};
    pyv[jp] = (v2f){r0.y, r1.y};
    pzv[jp] = (v2f){r0.z, r1.z};
    lpxyz[p0] = r0;
    lpxyz[p0 + 1] = r1;
    dv[jp] = (v2f){__builtin_inff(), __builtin_inff()};
  }
  // Prime parity-0 slots: slot 0 = (+inf, idx 0) wins the first compare.
  if (tid < FPS_WAVES)
    slots[0][tid] = (tid == 0) ? (((u64)0x7f800000u << 32) | 8191u) : 0ull;

  for (int it = 0; it < NPOINT; ++it) {
    lgkm_barrier();  // separates slot writes (it-1) from reads (it);
                     // LDS-only drain -- publish stores stay in flight
    // Read all 8 wave keys (broadcast, 4x ds_read_b128), 7-compare u64 max.
    const ulonglong2* sp =
        reinterpret_cast<const ulonglong2*>(&slots[it & 1][0]);
    const ulonglong2 s01 = sp[0];
    const ulonglong2 s23 = sp[1];
    const ulonglong2 s45 = sp[2];
    const ulonglong2 s67 = sp[3];
    u64 ka = (s01.y > s01.x) ? s01.y : s01.x;
    u64 kb = (s23.y > s23.x) ? s23.y : s23.x;
    u64 kc = (s45.y > s45.x) ? s45.y : s45.x;
    u64 kd = (s67.y > s67.x) ? s67.y : s67.x;
    ka = (kb > ka) ? kb : ka;
    kc = (kd > kc) ? kd : kc;
    const u64 k = (kc > ka) ? kc : ka;
    const int gi = 8191 - (int)(unsigned)k;  // low 32 bits = 8191-idx
    // Winner coords: broadcast LDS read.
    const float4 g = lpxyz[gi];
    const float gx = g.x, gy = g.y, gz = g.z;
    if (tid == 0) {  // publish winner: 3 sc1 dwords, fire-and-forget
      st_sc1(&gnew[it * 3 + 0], gx);
      st_sc1(&gnew[it * 3 + 1], gy);
      st_sc1(&gnew[it * 3 + 2], gz);
    }
    // Distance update (packed pairs; exact IEEE per-element) + in-loop
    // pair-granular tracking (bestjp + bestx; hidden under loop ILP).
    float bestv = -1.0f;
    float bestx = -1.0f;
    int bestjp = 0;
#pragma unroll
    for (int jp = 0; jp < PAIRS; ++jp) {
      v2f dx = pxv[jp] - gx;
      v2f dy = pyv[jp] - gy;
      v2f dz = pzv[jp] - gz;
      v2f nd = (dx * dx + dy * dy) + dz * dz;
      v2f dn = {fminf(dv[jp].x, nd.x), fminf(dv[jp].y, nd.y)};
      dv[jp] = dn;
      float pm = fmaxf(dn.x, dn.y);
      bool t = pm > bestv;  // strict: lowest jp wins ties
      bestjp = t ? jp : bestjp;
      bestx = t ? dn.x : bestx;
      bestv = fmaxf(bestv, pm);
    }
    // Within-pair parity: .x first (lower index) on ties.
    const int bestj = 2 * bestjp + ((bestx == bestv) ? 0 : 1);
    const unsigned besti = (unsigned)(tid * PTS_PER_THREAD + bestj);
    // Wave max via 6 DPP rounds -> lane 63; ballot -> lowest matching lane.
    float wm = bestv;
    wm = dpp_fmax<0x111>(wm);  // row_shr:1
    wm = dpp_fmax<0x112>(wm);  // row_shr:2
    wm = dpp_fmax<0x114>(wm);  // row_shr:4
    wm = dpp_fmax<0x118>(wm);  // row_shr:8
    wm = dpp_fmax<0x142>(wm);  // row_bcast15
    wm = dpp_fmax<0x143>(wm);  // row_bcast31
    const float swm =
        __int_as_float(__builtin_amdgcn_readlane(__float_as_int(wm), 63));
    const u64 wbal = __ballot(bestv == swm);
    const int wl = (int)__builtin_ctzll(wbal);
    if (lane == wl) {  // tiny tail: pack + one ds_write_b64
      slots[(it + 1) & 1][wv] =
          ((u64)__float_as_uint(bestv) << 32) | (8191u - besti);
    }
  }
  // No epilogue: newxyz fully published in-loop; dispatch completion
  // guarantees all stores retire before host readback.
}

extern "C" void kernel_launch(void* const* d_in, const int* in_sizes, int n_in,
                              void* d_out, int out_size, void* d_ws,
                              size_t ws_size, hipStream_t stream) {
  (void)in_sizes;
  (void)n_in;
  (void)out_size;
  (void)d_ws;
  (void)ws_size;
  const float* in = (const float*)d_in[0];
  float* out = (float*)d_out;
  // Poison newxyz with SENT (0xFF bytes = -NaN) so data doubles as the
  // readiness flag. Stream-ordered: completes before the kernel starts.
  hipMemsetAsync(out + OFF_NEWXYZ, 0xFF, (size_t)NB * NPOINT * 3 * sizeof(float),
                 stream);
  fused_kernel<<<NB + BQ_BLOCKS, FPS_THREADS, 0, stream>>>(in, out);
}